// Round 8
// baseline (519.269 us; speedup 1.0000x reference)
//
#include <hip/hip_runtime.h>
#include <hip/hip_bf16.h>
#include <stdint.h>

#define NROWS 262144

typedef __bf16 bf16x8 __attribute__((ext_vector_type(8)));
typedef float f32x4 __attribute__((ext_vector_type(4)));
typedef float f32x16 __attribute__((ext_vector_type(16)));

#define MFMA16(a,b,c) __builtin_amdgcn_mfma_f32_16x16x32_bf16(a,b,c,0,0,0)
#define MFMA32(a,b,c) __builtin_amdgcn_mfma_f32_32x32x16_bf16(a,b,c,0,0,0)

// ws images
#define WS_WP 0          // 512KB: d*16384 + plane*8192 + oct*512 + p*16 (A-frag image, 32x32x16)
#define WS_W1 524288     // 64KB:  kr*16384 + plane*8192 + (q*128+n)*16
#define WS_W0 589824     // 16KB:  plane*8192 + (g*128+n)*16
#define WS_BP 606208     // 4KB:   bp padded 25->32 per dim (f32)
// NOTE: ALL Wp cols (0..24) and bp entries are prescaled by 1/ln2 at prep:
//  - w/h logits (0..15): softmax runs on raw v_exp_f32 (2^x), no max-subtract
//  - deriv logits (16..24): softplus runs in exp2/log2 domain, x1 ln2 fma at end

// LDS (49152 B -> 3 blocks/CU):
//  W1A @0      16KB: W1 kr0, then kr2; phase3 h2 hi plane
//  W1B @16384  16KB: W1 kr1, then kr3; phase3 h2 lo plane
//  XM  @32768   8KB: xm hi/lo planes -> h1 stripe scratch (2KB/wave) -> yu
//  XU  @40960   8KB: xu [dim:32][row:64] f32 -> ld partials (epilogue)
#define W1A 0
#define W1B 16384
#define XM  32768
#define XU  40960

// manual RNE bf16 convert (R0-proven codegen)
__device__ __forceinline__ unsigned short f2bf(float f){
    unsigned int u = __float_as_uint(f);
    u = (u + 0x7FFFu + ((u >> 16) & 1u)) >> 16;
    return (unsigned short)u;
}
__device__ __forceinline__ float bf2f(unsigned short h){
    return __uint_as_float(((unsigned int)h) << 16);
}

__global__ __launch_bounds__(256) void prep_kernel(
    const float* __restrict__ W0, const float* __restrict__ W1,
    const float* __restrict__ Wp, const float* __restrict__ bp,
    char* __restrict__ ws)
{
    int tid = blockIdx.x * 256 + threadIdx.x;   // grid 152 -> 38912 threads
    if (tid < 32768){                            // Wp A-frag image (prescaled 1/ln2)
        int d = tid >> 10, r = tid & 1023;
        int plane = r >> 9, oct = (r >> 5) & 15, p = r & 31;
        unsigned short cell[8];
        #pragma unroll
        for (int j = 0; j < 8; j++){
            int k = oct*8 + j;
            float v = (p < 25) ? Wp[k*800 + d*25 + p] * 1.44269504f : 0.f;
            unsigned short hi = f2bf(v);
            cell[j] = plane ? f2bf(v - bf2f(hi)) : hi;
        }
        *(uint4*)(ws + WS_WP + d*16384 + plane*8192 + oct*512 + p*16) = *(uint4*)cell;
    } else if (tid < 36864){                     // W1 rounds
        int i = tid - 32768;
        int kr = i >> 10, r = i & 1023;
        int plane = r >> 9, q = (r >> 7) & 3, n = r & 127;
        unsigned short cell[8];
        #pragma unroll
        for (int j = 0; j < 8; j++){
            int k = kr*32 + q*8 + j;
            float v = W1[k*128 + n];
            unsigned short hi = f2bf(v);
            cell[j] = plane ? f2bf(v - bf2f(hi)) : hi;
        }
        *(uint4*)(ws + WS_W1 + kr*16384 + plane*8192 + (q*128+n)*16) = *(uint4*)cell;
    } else if (tid < 37888){                     // W0
        int i = tid - 36864;
        int plane = i >> 9, g = (i >> 7) & 3, n = i & 127;
        unsigned short cell[8];
        #pragma unroll
        for (int j = 0; j < 8; j++){
            int k = g*8 + j;
            float v = W0[k*128 + n];
            unsigned short hi = f2bf(v);
            cell[j] = plane ? f2bf(v - bf2f(hi)) : hi;
        }
        *(uint4*)(ws + WS_W0 + plane*8192 + (g*128+n)*16) = *(uint4*)cell;
    } else if (tid < 38912){                     // bp padded (prescaled 1/ln2)
        int i = tid - 37888;
        int d = i >> 5, n = i & 31;
        ((float*)(ws + WS_BP))[i] = (n < 25) ? bp[d*25 + n] * 1.44269504f : 0.f;
    }
}

__global__ __launch_bounds__(256, 3) void main_kernel(
    const float* __restrict__ x,
    const float* __restrict__ pb0, const float* __restrict__ pg0, const float* __restrict__ pbe0,
    const float* __restrict__ pb1, const float* __restrict__ pg1, const float* __restrict__ pbe1,
    const char* __restrict__ ws,
    float* __restrict__ yout, float* __restrict__ ldout)
{
    __shared__ __align__(16) char smem[49152];
    const int t = threadIdx.x;
    const int r0 = blockIdx.x * 64;
    const int w = t >> 6, lane = t & 63, l16 = lane & 15, q = lane >> 4;
    const f32x4 fzero = {0.f, 0.f, 0.f, 0.f};

    auto stage16k = [&](int dstoff, int srcoff){
        #pragma unroll
        for (int k = 0; k < 4; k++){
            int cell = t + 256*k;
            ((uint4*)(smem + dstoff))[cell] = ((const uint4*)(ws + srcoff))[cell];
        }
    };

    // ---------------- phase 0: W0 frags direct from L2; x -> xm/xu; stage W1 kr0+kr1 ----------------
    uint4 w0h[8], w0l[8];
    #pragma unroll
    for (int nt = 0; nt < 8; nt++){
        int n = nt*16 + l16;
        w0h[nt] = *(const uint4*)(ws + WS_W0 + (q*128 + n)*16);
        w0l[nt] = *(const uint4*)(ws + WS_W0 + 8192 + (q*128 + n)*16);
    }
    #pragma unroll
    for (int k = 0; k < 4; k++){
        int i = t + 256*k;
        int row = i >> 4, s = i & 15;
        float4 v = ((const float4*)(x + (size_t)(r0 + row) * 64))[s];
        unsigned short h0 = f2bf(v.x), h1s = f2bf(v.z);
        unsigned short l0 = f2bf(v.x - bf2f(h0)), l1 = f2bf(v.z - bf2f(h1s));
        int g = s >> 2, ofs = (s & 3) * 4;
        *(unsigned int*)(smem + XM + (g*64 + row)*16 + ofs) = (unsigned int)h0 | ((unsigned int)h1s << 16);
        *(unsigned int*)(smem + XM + 4096 + (g*64 + row)*16 + ofs) = (unsigned int)l0 | ((unsigned int)l1 << 16);
        *(float*)(smem + XU + ((2*s)*64 + row)*4) = v.y;
        *(float*)(smem + XU + ((2*s+1)*64 + row)*4) = v.w;
    }
    stage16k(W1A, WS_W1);                  // kr0
    stage16k(W1B, WS_W1 + 16384);          // kr1
    __syncthreads();

    // ---------------- phase 1: GEMM0 (split bf16x3) + LN0 + relu ----------------
    float h1r[8][4];
    {
        bf16x8 a_h = *(const bf16x8*)(smem + XM + (q*64 + 16*w + l16)*16);
        bf16x8 a_l = *(const bf16x8*)(smem + XM + 4096 + (q*64 + 16*w + l16)*16);
        f32x4 c0[8];
        #pragma unroll
        for (int nt = 0; nt < 8; nt++){
            bf16x8 b_h = *(bf16x8*)&w0h[nt];
            bf16x8 b_l = *(bf16x8*)&w0l[nt];
            f32x4 acc = fzero;
            acc = MFMA16(a_h, b_l, acc);
            acc = MFMA16(a_l, b_h, acc);
            acc = MFMA16(a_h, b_h, acc);
            c0[nt] = acc;
        }
        float s1[4] = {0,0,0,0}, s2[4] = {0,0,0,0};
        #pragma unroll
        for (int nt = 0; nt < 8; nt++){
            float bv = pb0[nt*16 + l16];
            #pragma unroll
            for (int rg = 0; rg < 4; rg++){
                float v = c0[nt][rg] + bv;
                c0[nt][rg] = v; s1[rg] += v; s2[rg] += v*v;
            }
        }
        #pragma unroll
        for (int m = 1; m < 16; m <<= 1)
            #pragma unroll
            for (int rg = 0; rg < 4; rg++){
                s1[rg] += __shfl_xor(s1[rg], m, 64);
                s2[rg] += __shfl_xor(s2[rg], m, 64);
            }
        #pragma unroll
        for (int rg = 0; rg < 4; rg++){
            float mean = s1[rg] * 0.0078125f;
            float var  = s2[rg] * 0.0078125f - mean*mean;
            s1[rg] = mean; s2[rg] = rsqrtf(var + 1e-6f);
        }
        #pragma unroll
        for (int nt = 0; nt < 8; nt++){
            float gv = pg0[nt*16 + l16], bev = pbe0[nt*16 + l16];
            #pragma unroll
            for (int rg = 0; rg < 4; rg++){
                float hv = (c0[nt][rg] - s1[rg]) * s2[rg] * gv + bev;
                h1r[nt][rg] = fmaxf(hv, 0.f);
            }
        }
    }
    __syncthreads();   // xm region now free (stripe scratch)

    // wave-local transpose of h1 -> A-frag registers (2KB stripe, half-K passes)
    bf16x8 ah1[4], al1[4];
    {
        char* sb = smem + XM + w*2048;
        #pragma unroll
        for (int half = 0; half < 2; half++){
            #pragma unroll
            for (int nt = half*4; nt < half*4 + 4; nt++){
                int col = nt*16 + l16;
                int gg = (col >> 3) - half*8;
                #pragma unroll
                for (int rg = 0; rg < 4; rg++)
                    *(unsigned short*)(sb + (gg*16 + q*4+rg)*16 + (col&7)*2) = f2bf(h1r[nt][rg]);
            }
            #pragma unroll
            for (int kr = half*2; kr < half*2 + 2; kr++)
                ah1[kr] = *(const bf16x8*)(sb + (((kr*4+q) - half*8)*16 + l16)*16);
        }
        #pragma unroll
        for (int half = 0; half < 2; half++){
            #pragma unroll
            for (int nt = half*4; nt < half*4 + 4; nt++){
                int col = nt*16 + l16;
                int gg = (col >> 3) - half*8;
                #pragma unroll
                for (int rg = 0; rg < 4; rg++){
                    unsigned short hi = f2bf(h1r[nt][rg]);
                    *(unsigned short*)(sb + (gg*16 + q*4+rg)*16 + (col&7)*2) = f2bf(h1r[nt][rg] - bf2f(hi));
                }
            }
            #pragma unroll
            for (int kr = half*2; kr < half*2 + 2; kr++)
                al1[kr] = *(const bf16x8*)(sb + (((kr*4+q) - half*8)*16 + l16)*16);
        }
    }

    // ---------------- phase 2: GEMM1 (4 K-rounds, split bf16x3) ----------------
    f32x4 c1[8];
    #pragma unroll
    for (int nt = 0; nt < 8; nt++) c1[nt] = fzero;
    auto g1round = [&](int base, bf16x8 ah, bf16x8 al){
        #pragma unroll
        for (int nt = 0; nt < 8; nt++){
            int n = nt*16 + l16;
            bf16x8 bhv = *(const bf16x8*)(smem + base + (q*128 + n)*16);
            bf16x8 blv = *(const bf16x8*)(smem + base + 8192 + (q*128 + n)*16);
            c1[nt] = MFMA16(ah, blv, c1[nt]);
            c1[nt] = MFMA16(al, bhv, c1[nt]);
            c1[nt] = MFMA16(ah, bhv, c1[nt]);
        }
    };
    g1round(W1A, ah1[0], al1[0]);
    g1round(W1B, ah1[1], al1[1]);
    __syncthreads();
    stage16k(W1A, WS_W1 + 32768);          // kr2
    stage16k(W1B, WS_W1 + 49152);          // kr3
    __syncthreads();
    g1round(W1A, ah1[2], al1[2]);
    g1round(W1B, ah1[3], al1[3]);

    // LN1 + relu + residual -> h2 (into h1r)
    {
        float s1[4] = {0,0,0,0}, s2[4] = {0,0,0,0};
        #pragma unroll
        for (int nt = 0; nt < 8; nt++){
            float bv = pb1[nt*16 + l16];
            #pragma unroll
            for (int rg = 0; rg < 4; rg++){
                float v = c1[nt][rg] + bv;
                c1[nt][rg] = v; s1[rg] += v; s2[rg] += v*v;
            }
        }
        #pragma unroll
        for (int m = 1; m < 16; m <<= 1)
            #pragma unroll
            for (int rg = 0; rg < 4; rg++){
                s1[rg] += __shfl_xor(s1[rg], m, 64);
                s2[rg] += __shfl_xor(s2[rg], m, 64);
            }
        #pragma unroll
        for (int rg = 0; rg < 4; rg++){
            float mean = s1[rg] * 0.0078125f;
            float var  = s2[rg] * 0.0078125f - mean*mean;
            s1[rg] = mean; s2[rg] = rsqrtf(var + 1e-6f);
        }
        #pragma unroll
        for (int nt = 0; nt < 8; nt++){
            float gv = pg1[nt*16 + l16], bev = pbe1[nt*16 + l16];
            #pragma unroll
            for (int rg = 0; rg < 4; rg++){
                float hv = (c1[nt][rg] - s1[rg]) * s2[rg] * gv + bev;
                h1r[nt][rg] = fmaxf(hv, 0.f) + h1r[nt][rg];
            }
        }
    }
    __syncthreads();   // all waves done reading W1A/W1B

    // ---------------- h2 -> block-wide transposed planes (hi @W1A, lo @W1B) ----------------
    #pragma unroll
    for (int nt = 0; nt < 8; nt++){
        int k = nt*16 + l16;
        #pragma unroll
        for (int rg = 0; rg < 4; rg++){
            int row = 16*w + q*4 + rg;
            float val = h1r[nt][rg];
            unsigned short hi = f2bf(val);
            int addr = row*256 + ((((k>>3) ^ (row&15)) & 15)*16) + (k&7)*2;
            *(unsigned short*)(smem + W1A + addr) = hi;
            *(unsigned short*)(smem + W1B + addr) = f2bf(val - bf2f(hi));
        }
    }
    __syncthreads();

    // ---------------- phase 3: wave-independent, 8 dims/wave, no barriers ----------------
    const char* wpl = ws + WS_WP + lane*16;
    const float* bpf = (const float*)(ws + WS_BP);
    float* xuLf = (float*)(smem + XU);
    float* yuLf = (float*)(smem + XM);
    const uint4 zero4 = {0,0,0,0};
    const bool pok = (lane & 31) < 25;
    const int hh = lane >> 5;
    const int d0 = w*8;
    const int rA = (lane & 31)*256, rB = (32 + (lane & 31))*256;
    auto rdB = [&](int pl, int rbase, int oct){
        return *(const bf16x8*)(smem + pl + rbase + (((oct ^ l16) & 15)*16));
    };

    // hoist loop-invariant rA-tile B-frags into registers (16 b128 once, vs per-iter)
    bf16x8 BAh[8], BAl[8];
    #pragma unroll
    for (int kk = 0; kk < 8; kk++){
        int oct = kk*2 + hh;
        BAh[kk] = rdB(W1A, rA, oct);
        BAl[kk] = rdB(W1B, rA, oct);
    }

    uint4 A0[8], A1[8];
    #pragma unroll
    for (int kk = 0; kk < 8; kk++){ A0[kk] = zero4; A1[kk] = zero4; }
    if (pok){
        #pragma unroll
        for (int kk = 0; kk < 4; kk++){
            A0[kk]   = *(const uint4*)(wpl + d0*16384 + kk*1024);
            A0[4+kk] = *(const uint4*)(wpl + d0*16384 + 8192 + kk*1024);
        }
    }
    float ld_acc = 0.f;   // accumulated in log2 units; x ln2 at epilogue
    for (int i = 0; i < 8; i++){
        int c = d0 + i;
        if (pok){
            #pragma unroll
            for (int kk = 0; kk < 4; kk++){
                A1[kk]   = *(const uint4*)(wpl + c*16384 + (4+kk)*1024);
                A1[4+kk] = *(const uint4*)(wpl + c*16384 + 8192 + (4+kk)*1024);
            }
        }
        f32x16 t0, t1;
        #pragma unroll
        for (int z = 0; z < 16; z++){ t0[z] = 0.f; t1[z] = 0.f; }
        #pragma unroll
        for (int kk = 0; kk < 4; kk++){
            int oct = kk*2 + hh;
            bf16x8 ahh = *(bf16x8*)&A0[kk];
            bf16x8 all = *(bf16x8*)&A0[4+kk];
            bf16x8 b1h = rdB(W1A, rB, oct), b1l = rdB(W1B, rB, oct);
            t0 = MFMA32(ahh, BAl[kk], t0); t1 = MFMA32(ahh, b1l, t1);
            t0 = MFMA32(all, BAh[kk], t0); t1 = MFMA32(all, b1h, t1);
            t0 = MFMA32(ahh, BAh[kk], t0); t1 = MFMA32(ahh, b1h, t1);
        }
        if (i < 7 && pok){
            #pragma unroll
            for (int kk = 0; kk < 4; kk++){
                A0[kk]   = *(const uint4*)(wpl + (c+1)*16384 + kk*1024);
                A0[4+kk] = *(const uint4*)(wpl + (c+1)*16384 + 8192 + kk*1024);
            }
        }
        #pragma unroll
        for (int kk = 0; kk < 4; kk++){
            int oct = (4+kk)*2 + hh;
            bf16x8 ahh = *(bf16x8*)&A1[kk];
            bf16x8 all = *(bf16x8*)&A1[4+kk];
            bf16x8 b1h = rdB(W1A, rB, oct), b1l = rdB(W1B, rB, oct);
            t0 = MFMA32(ahh, BAl[4+kk], t0); t1 = MFMA32(ahh, b1l, t1);
            t0 = MFMA32(all, BAh[4+kk], t0); t1 = MFMA32(all, b1h, t1);
            t0 = MFMA32(ahh, BAh[4+kk], t0); t1 = MFMA32(ahh, b1h, t1);
        }
        // ---- pairwise spline: lanes (L, L^32) jointly handle rows L&31 (tile0) and 32+(L&31) (tile1)
        float xu0 = xuLf[c*64 + (lane & 31)];
        float xu1 = xuLf[c*64 + 32 + (lane & 31)];
        float xc0 = __builtin_amdgcn_fmed3f(xu0, -3.f, 3.f);
        float xc1 = __builtin_amdgcn_fmed3f(xu1, -3.f, 3.f);
        float4 bq0 = *(const float4*)(bpf + c*32 + 0  + 4*hh);
        float4 bq1 = *(const float4*)(bpf + c*32 + 8  + 4*hh);
        float4 bq2 = *(const float4*)(bpf + c*32 + 16 + 4*hh);
        float  bq3 = bpf[c*32 + 24 + 4*hh];
        float wv0[4], wv1[4], hv0[4], hv1[4], dv0[4], dv1[4];
        #pragma unroll
        for (int jj = 0; jj < 4; jj++){
            wv0[jj] = t0[jj] + bq0[jj];  hv0[jj] = t0[4+jj] + bq1[jj];  dv0[jj] = t0[8+jj] + bq2[jj];
            wv1[jj] = t1[jj] + bq0[jj];  hv1[jj] = t1[4+jj] + bq1[jj];  dv1[jj] = t1[8+jj] + bq2[jj];
        }
        float dx0 = t0[12] + bq3, dx1 = t1[12] + bq3;
        float bd0 = __shfl_xor(hh ? dv0[0] : dx0, 32, 64);
        float bd1 = __shfl_xor(hh ? dv1[0] : dx1, 32, 64);
        // softmax without max-subtraction (logits prescaled to exp2 domain)
        auto softscale = [&](float* a){
            float e0 = __builtin_amdgcn_exp2f(a[0]), e1 = __builtin_amdgcn_exp2f(a[1]);
            float e2 = __builtin_amdgcn_exp2f(a[2]), e3 = __builtin_amdgcn_exp2f(a[3]);
            float s = (e0+e1)+(e2+e3);
            s += __shfl_xor(s, 32, 64);
            float sc = 5.952f * __builtin_amdgcn_rcpf(s);
            a[0] = fmaf(e0, sc, 0.006f); a[1] = fmaf(e1, sc, 0.006f);
            a[2] = fmaf(e2, sc, 0.006f); a[3] = fmaf(e3, sc, 0.006f);
        };
        softscale(wv0); softscale(hv0); softscale(wv1); softscale(hv1);
        auto candf = [&](float* wv, float* hv, float* dv, float bdr, float xc,
                         float& X, float& Y, float& W, float& H, float& DK, float& DK1, float& V){
            float pw0 = wv[0], pw1 = pw0+wv[1], pw2 = pw1+wv[2], pw3 = pw2+wv[3];
            float ph0 = hv[0], ph1 = ph0+hv[1], ph2 = ph1+hv[2], ph3 = ph2+hv[3];
            float offw = __shfl_xor(pw3, 32, 64);
            float offh = __shfl_xor(ph3, 32, 64);
            float bw = hh ? (offw - 3.f) : -3.f;
            float by = hh ? (offh - 3.f) : -3.f;
            X = bw; Y = by; W = wv[0]; H = hv[0]; DK = dv[0]; DK1 = dv[1];
            float e1_ = bw + pw0, e2_ = bw + pw1, e3_ = bw + pw2;
            if (xc >= e1_){ X = e1_; Y = by + ph0; W = wv[1]; H = hv[1]; DK = dv[1]; DK1 = dv[2]; }
            if (xc >= e2_){ X = e2_; Y = by + ph1; W = wv[2]; H = hv[2]; DK = dv[2]; DK1 = dv[3]; }
            if (xc >= e3_){ X = e3_; Y = by + ph2; W = wv[3]; H = hv[3]; DK = dv[3]; DK1 = bdr;  }
            V = (!hh || xc >= bw) ? 1.f : 0.f;
        };
        float X0,Y0,Wc0,Hc0,K0,K10,V0, X1,Y1,Wc1,Hc1,K1,K11,V1;
        candf(wv0, hv0, dv0, bd0, xc0, X0,Y0,Wc0,Hc0,K0,K10,V0);
        candf(wv1, hv1, dv1, bd1, xc1, X1,Y1,Wc1,Hc1,K1,K11,V1);
        float rX  = __shfl_xor(hh ? X0  : X1 , 32, 64);
        float rY  = __shfl_xor(hh ? Y0  : Y1 , 32, 64);
        float rW  = __shfl_xor(hh ? Wc0 : Wc1, 32, 64);
        float rH  = __shfl_xor(hh ? Hc0 : Hc1, 32, 64);
        float rK  = __shfl_xor(hh ? K0  : K1 , 32, 64);
        float rK1 = __shfl_xor(hh ? K10 : K11, 32, 64);
        float rV  = __shfl_xor(hh ? V0  : V1 , 32, 64);
        float oX  = hh ? X1  : X0,  oY  = hh ? Y1  : Y0,  oW = hh ? Wc1 : Wc0;
        float oH  = hh ? Hc1 : Hc0, oK  = hh ? K1  : K0,  oK1 = hh ? K11 : K10;
        float oV  = hh ? V1  : V0;
        bool useh1 = ((hh ? oV : rV) > 0.5f);
        bool useOwn = (hh != 0) == useh1;
        float X = useOwn ? oX : rX,  Y = useOwn ? oY : rY;
        float W = useOwn ? oW : rW,  H = useOwn ? oH : rH;
        float K = useOwn ? oK : rK,  K1s = useOwn ? oK1 : rK1;
        float xu = hh ? xu1 : xu0;
        float xc = hh ? xc1 : xc0;
        // softplus in exp2/log2 domain (K, K1s arrive prescaled by 1/ln2):
        // softplus_e(k) = ln2 * (max(k',0) + log2(1 + 2^-|k'|)),  k' = k/ln2
        float DKs  = fmaf(0.69314718f,
                          fmaxf(K, 0.f)   + __builtin_amdgcn_logf(1.f + __builtin_amdgcn_exp2f(-fabsf(K))),
                          0.001f);
        float DK1s = fmaf(0.69314718f,
                          fmaxf(K1s, 0.f) + __builtin_amdgcn_logf(1.f + __builtin_amdgcn_exp2f(-fabsf(K1s))),
                          0.001f);
        float iw = __builtin_amdgcn_rcpf(W);
        float s_ = H * iw;
        float th = (xc - X) * iw;
        float om = 1.f - th;
        float t1m = th * om;
        float den = s_ + (DK1s + DKs - 2.f*s_) * t1m;
        float rden = __builtin_amdgcn_rcpf(den);
        float yin = Y + H * (s_*th*th + DKs*t1m) * rden;
        float num2 = DK1s*th*th + 2.f*s_*t1m + DKs*om*om;
        // ldin = ln(s^2 * num2 / den^2) -> accumulate log2, scale once at end
        float P = (s_*s_) * num2 * (rden*rden);
        bool inside = (xu > -3.f) && (xu < 3.f);
        yuLf[c*64 + lane] = inside ? yin : xu;   // lane L finalizes global row L
        ld_acc += inside ? __builtin_amdgcn_logf(P) : 0.f;
    }

    // ---------------- epilogue ----------------
    __syncthreads();                       // xu dead; yu complete
    *(float*)(smem + XU + (w*64 + lane)*4) = ld_acc;
    __syncthreads();
    if (t < 64){
        const float* lp = (const float*)(smem + XU);
        ldout[r0 + t] = ((lp[t] + lp[64 + t]) + (lp[128 + t] + lp[192 + t])) * 0.69314718f;
    }
    {
        int row = t >> 2, part = t & 3;
        const float* xrow = x + (size_t)(r0 + row)*64;
        float* yrow = yout + (size_t)(r0 + row)*64;
        const float* yuL = (const float*)(smem + XM);
        #pragma unroll
        for (int j = 0; j < 4; j++){
            int s = part*4 + j;
            float4 xv = ((const float4*)xrow)[s];
            float4 o;
            o.x = xv.x; o.z = xv.z;
            o.y = yuL[(2*s)*64 + row];
            o.w = yuL[(2*s+1)*64 + row];
            ((float4*)yrow)[s] = o;
        }
    }
}

extern "C" void kernel_launch(void* const* d_in, const int* in_sizes, int n_in,
                              void* d_out, int out_size, void* d_ws, size_t ws_size,
                              hipStream_t stream)
{
    const float* x   = (const float*)d_in[0];
    const float* W0  = (const float*)d_in[1];
    const float* b0  = (const float*)d_in[2];
    const float* g0  = (const float*)d_in[3];
    const float* be0 = (const float*)d_in[4];
    const float* W1  = (const float*)d_in[5];
    const float* b1  = (const float*)d_in[6];
    const float* g1  = (const float*)d_in[7];
    const float* be1 = (const float*)d_in[8];
    const float* Wp  = (const float*)d_in[9];
    const float* bp  = (const float*)d_in[10];
    float* y = (float*)d_out;
    float* ldo = y + (size_t)NROWS * 64;
    char* ws = (char*)d_ws;

    hipLaunchKernelGGL(prep_kernel, dim3(152), dim3(256), 0, stream, W0, W1, Wp, bp, ws);
    hipLaunchKernelGGL(main_kernel, dim3(4096), dim3(256), 0, stream,
                       x, b0, g0, be0, b1, g1, be1, ws, y, ldo);
}

// Round 12
// 370.143 us; speedup vs baseline: 1.4029x; 1.4029x over previous
//
#include <hip/hip_runtime.h>
#include <hip/hip_bf16.h>
#include <stdint.h>

#define NROWS 262144

typedef __bf16 bf16x8 __attribute__((ext_vector_type(8)));
typedef float f32x4 __attribute__((ext_vector_type(4)));
typedef float f32x16 __attribute__((ext_vector_type(16)));

#define MFMA16(a,b,c) __builtin_amdgcn_mfma_f32_16x16x32_bf16(a,b,c,0,0,0)
#define MFMA32(a,b,c) __builtin_amdgcn_mfma_f32_32x32x16_bf16(a,b,c,0,0,0)

// ws images
#define WS_WP 0          // 512KB: d*16384 + plane*8192 + oct*512 + p*16 (A-frag image, 32x32x16)
#define WS_W1 524288     // 64KB:  kr*16384 + plane*8192 + (q*128+n)*16
#define WS_W0 589824     // 16KB:  plane*8192 + (g*128+n)*16
#define WS_BP 606208     // 4KB:   bp padded 25->32 per dim (f32)
// NOTE: Wp cols 0..15 (w/h logits) and matching bp entries are prescaled by
// 1/ln2 at prep time; phase-3 softmax then uses raw v_exp_f32 (2^x) with no
// per-element multiply and NO max-subtraction (logits are LN-bounded, exp-safe).
// BOTH h2 planes retained in phase 3 (R11 lesson: log_det sums 32 dims ->
// sqrt(32) error amplification makes the lo-plane drop unsafe).

// LDS (49152 B -> 3 blocks/CU):
//  W1A @0      16KB: W1 kr0, then kr2; phase3 h2 hi plane
//  W1B @16384  16KB: W1 kr1, then kr3; phase3 h2 lo plane
//  XM  @32768   8KB: xm hi/lo planes -> h1 stripe scratch (2KB/wave) -> yu
//  XU  @40960   8KB: xu [dim:32][row:64] f32 -> ld partials (epilogue)
#define W1A 0
#define W1B 16384
#define XM  32768
#define XU  40960

// manual RNE bf16 convert (R0-proven codegen)
__device__ __forceinline__ unsigned short f2bf(float f){
    unsigned int u = __float_as_uint(f);
    u = (u + 0x7FFFu + ((u >> 16) & 1u)) >> 16;
    return (unsigned short)u;
}
__device__ __forceinline__ float bf2f(unsigned short h){
    return __uint_as_float(((unsigned int)h) << 16);
}

__global__ __launch_bounds__(256) void prep_kernel(
    const float* __restrict__ W0, const float* __restrict__ W1,
    const float* __restrict__ Wp, const float* __restrict__ bp,
    char* __restrict__ ws)
{
    int tid = blockIdx.x * 256 + threadIdx.x;   // grid 152 -> 38912 threads
    if (tid < 32768){                            // Wp A-frag image
        int d = tid >> 10, r = tid & 1023;
        int plane = r >> 9, oct = (r >> 5) & 15, p = r & 31;
        unsigned short cell[8];
        #pragma unroll
        for (int j = 0; j < 8; j++){
            int k = oct*8 + j;
            float v = (p < 25) ? Wp[k*800 + d*25 + p] : 0.f;
            if (p < 16) v *= 1.44269504f;        // w/h logit cols -> exp2 domain
            unsigned short hi = f2bf(v);
            cell[j] = plane ? f2bf(v - bf2f(hi)) : hi;
        }
        *(uint4*)(ws + WS_WP + d*16384 + plane*8192 + oct*512 + p*16) = *(uint4*)cell;
    } else if (tid < 36864){                     // W1 rounds
        int i = tid - 32768;
        int kr = i >> 10, r = i & 1023;
        int plane = r >> 9, q = (r >> 7) & 3, n = r & 127;
        unsigned short cell[8];
        #pragma unroll
        for (int j = 0; j < 8; j++){
            int k = kr*32 + q*8 + j;
            float v = W1[k*128 + n];
            unsigned short hi = f2bf(v);
            cell[j] = plane ? f2bf(v - bf2f(hi)) : hi;
        }
        *(uint4*)(ws + WS_W1 + kr*16384 + plane*8192 + (q*128+n)*16) = *(uint4*)cell;
    } else if (tid < 37888){                     // W0
        int i = tid - 36864;
        int plane = i >> 9, g = (i >> 7) & 3, n = i & 127;
        unsigned short cell[8];
        #pragma unroll
        for (int j = 0; j < 8; j++){
            int k = g*8 + j;
            float v = W0[k*128 + n];
            unsigned short hi = f2bf(v);
            cell[j] = plane ? f2bf(v - bf2f(hi)) : hi;
        }
        *(uint4*)(ws + WS_W0 + plane*8192 + (g*128+n)*16) = *(uint4*)cell;
    } else if (tid < 38912){                     // bp padded
        int i = tid - 37888;
        int d = i >> 5, n = i & 31;
        float bv = (n < 25) ? bp[d*25 + n] : 0.f;
        if (n < 16) bv *= 1.44269504f;           // match Wp prescale
        ((float*)(ws + WS_BP))[i] = bv;
    }
}

__global__ __launch_bounds__(256, 3) void main_kernel(
    const float* __restrict__ x,
    const float* __restrict__ pb0, const float* __restrict__ pg0, const float* __restrict__ pbe0,
    const float* __restrict__ pb1, const float* __restrict__ pg1, const float* __restrict__ pbe1,
    const char* __restrict__ ws,
    float* __restrict__ yout, float* __restrict__ ldout)
{
    __shared__ __align__(16) char smem[49152];
    const int t = threadIdx.x;
    const int r0 = blockIdx.x * 64;
    const int w = t >> 6, lane = t & 63, l16 = lane & 15, q = lane >> 4;
    const f32x4 fzero = {0.f, 0.f, 0.f, 0.f};

    auto stage16k = [&](int dstoff, int srcoff){
        #pragma unroll
        for (int k = 0; k < 4; k++){
            int cell = t + 256*k;
            ((uint4*)(smem + dstoff))[cell] = ((const uint4*)(ws + srcoff))[cell];
        }
    };

    // ---------------- phase 0: W0 frags direct from L2; x -> xm/xu; stage W1 kr0+kr1 ----------------
    uint4 w0h[8], w0l[8];
    #pragma unroll
    for (int nt = 0; nt < 8; nt++){
        int n = nt*16 + l16;
        w0h[nt] = *(const uint4*)(ws + WS_W0 + (q*128 + n)*16);
        w0l[nt] = *(const uint4*)(ws + WS_W0 + 8192 + (q*128 + n)*16);
    }
    #pragma unroll
    for (int k = 0; k < 4; k++){
        int i = t + 256*k;
        int row = i >> 4, s = i & 15;
        float4 v = ((const float4*)(x + (size_t)(r0 + row) * 64))[s];
        unsigned short h0 = f2bf(v.x), h1s = f2bf(v.z);
        unsigned short l0 = f2bf(v.x - bf2f(h0)), l1 = f2bf(v.z - bf2f(h1s));
        int g = s >> 2, ofs = (s & 3) * 4;
        *(unsigned int*)(smem + XM + (g*64 + row)*16 + ofs) = (unsigned int)h0 | ((unsigned int)h1s << 16);
        *(unsigned int*)(smem + XM + 4096 + (g*64 + row)*16 + ofs) = (unsigned int)l0 | ((unsigned int)l1 << 16);
        *(float*)(smem + XU + ((2*s)*64 + row)*4) = v.y;
        *(float*)(smem + XU + ((2*s+1)*64 + row)*4) = v.w;
    }
    stage16k(W1A, WS_W1);                  // kr0
    stage16k(W1B, WS_W1 + 16384);          // kr1
    __syncthreads();

    // ---------------- phase 1: GEMM0 (split bf16x3) + LN0 + relu ----------------
    float h1r[8][4];
    {
        bf16x8 a_h = *(const bf16x8*)(smem + XM + (q*64 + 16*w + l16)*16);
        bf16x8 a_l = *(const bf16x8*)(smem + XM + 4096 + (q*64 + 16*w + l16)*16);
        f32x4 c0[8];
        #pragma unroll
        for (int nt = 0; nt < 8; nt++){
            bf16x8 b_h = *(bf16x8*)&w0h[nt];
            bf16x8 b_l = *(bf16x8*)&w0l[nt];
            f32x4 acc = fzero;
            acc = MFMA16(a_h, b_l, acc);
            acc = MFMA16(a_l, b_h, acc);
            acc = MFMA16(a_h, b_h, acc);
            c0[nt] = acc;
        }
        float s1[4] = {0,0,0,0}, s2[4] = {0,0,0,0};
        #pragma unroll
        for (int nt = 0; nt < 8; nt++){
            float bv = pb0[nt*16 + l16];
            #pragma unroll
            for (int rg = 0; rg < 4; rg++){
                float v = c0[nt][rg] + bv;
                c0[nt][rg] = v; s1[rg] += v; s2[rg] += v*v;
            }
        }
        #pragma unroll
        for (int m = 1; m < 16; m <<= 1)
            #pragma unroll
            for (int rg = 0; rg < 4; rg++){
                s1[rg] += __shfl_xor(s1[rg], m, 64);
                s2[rg] += __shfl_xor(s2[rg], m, 64);
            }
        #pragma unroll
        for (int rg = 0; rg < 4; rg++){
            float mean = s1[rg] * 0.0078125f;
            float var  = s2[rg] * 0.0078125f - mean*mean;
            s1[rg] = mean; s2[rg] = rsqrtf(var + 1e-6f);
        }
        #pragma unroll
        for (int nt = 0; nt < 8; nt++){
            float gv = pg0[nt*16 + l16], bev = pbe0[nt*16 + l16];
            #pragma unroll
            for (int rg = 0; rg < 4; rg++){
                float hv = (c0[nt][rg] - s1[rg]) * s2[rg] * gv + bev;
                h1r[nt][rg] = fmaxf(hv, 0.f);
            }
        }
    }
    __syncthreads();   // xm region now free (stripe scratch)

    // wave-local transpose of h1 -> A-frag registers (2KB stripe, half-K passes)
    bf16x8 ah1[4], al1[4];
    {
        char* sb = smem + XM + w*2048;
        #pragma unroll
        for (int half = 0; half < 2; half++){
            #pragma unroll
            for (int nt = half*4; nt < half*4 + 4; nt++){
                int col = nt*16 + l16;
                int gg = (col >> 3) - half*8;
                #pragma unroll
                for (int rg = 0; rg < 4; rg++)
                    *(unsigned short*)(sb + (gg*16 + q*4+rg)*16 + (col&7)*2) = f2bf(h1r[nt][rg]);
            }
            #pragma unroll
            for (int kr = half*2; kr < half*2 + 2; kr++)
                ah1[kr] = *(const bf16x8*)(sb + (((kr*4+q) - half*8)*16 + l16)*16);
        }
        #pragma unroll
        for (int half = 0; half < 2; half++){
            #pragma unroll
            for (int nt = half*4; nt < half*4 + 4; nt++){
                int col = nt*16 + l16;
                int gg = (col >> 3) - half*8;
                #pragma unroll
                for (int rg = 0; rg < 4; rg++){
                    unsigned short hi = f2bf(h1r[nt][rg]);
                    *(unsigned short*)(sb + (gg*16 + q*4+rg)*16 + (col&7)*2) = f2bf(h1r[nt][rg] - bf2f(hi));
                }
            }
            #pragma unroll
            for (int kr = half*2; kr < half*2 + 2; kr++)
                al1[kr] = *(const bf16x8*)(sb + (((kr*4+q) - half*8)*16 + l16)*16);
        }
    }

    // ---------------- phase 2: GEMM1 (4 K-rounds, split bf16x3) ----------------
    f32x4 c1[8];
    #pragma unroll
    for (int nt = 0; nt < 8; nt++) c1[nt] = fzero;
    auto g1round = [&](int base, bf16x8 ah, bf16x8 al){
        #pragma unroll
        for (int nt = 0; nt < 8; nt++){
            int n = nt*16 + l16;
            bf16x8 bhv = *(const bf16x8*)(smem + base + (q*128 + n)*16);
            bf16x8 blv = *(const bf16x8*)(smem + base + 8192 + (q*128 + n)*16);
            c1[nt] = MFMA16(ah, blv, c1[nt]);
            c1[nt] = MFMA16(al, bhv, c1[nt]);
            c1[nt] = MFMA16(ah, bhv, c1[nt]);
        }
    };
    g1round(W1A, ah1[0], al1[0]);
    g1round(W1B, ah1[1], al1[1]);
    __syncthreads();
    stage16k(W1A, WS_W1 + 32768);          // kr2
    stage16k(W1B, WS_W1 + 49152);          // kr3
    __syncthreads();
    g1round(W1A, ah1[2], al1[2]);
    g1round(W1B, ah1[3], al1[3]);

    // LN1 + relu + residual -> h2 (into h1r)
    {
        float s1[4] = {0,0,0,0}, s2[4] = {0,0,0,0};
        #pragma unroll
        for (int nt = 0; nt < 8; nt++){
            float bv = pb1[nt*16 + l16];
            #pragma unroll
            for (int rg = 0; rg < 4; rg++){
                float v = c1[nt][rg] + bv;
                c1[nt][rg] = v; s1[rg] += v; s2[rg] += v*v;
            }
        }
        #pragma unroll
        for (int m = 1; m < 16; m <<= 1)
            #pragma unroll
            for (int rg = 0; rg < 4; rg++){
                s1[rg] += __shfl_xor(s1[rg], m, 64);
                s2[rg] += __shfl_xor(s2[rg], m, 64);
            }
        #pragma unroll
        for (int rg = 0; rg < 4; rg++){
            float mean = s1[rg] * 0.0078125f;
            float var  = s2[rg] * 0.0078125f - mean*mean;
            s1[rg] = mean; s2[rg] = rsqrtf(var + 1e-6f);
        }
        #pragma unroll
        for (int nt = 0; nt < 8; nt++){
            float gv = pg1[nt*16 + l16], bev = pbe1[nt*16 + l16];
            #pragma unroll
            for (int rg = 0; rg < 4; rg++){
                float hv = (c1[nt][rg] - s1[rg]) * s2[rg] * gv + bev;
                h1r[nt][rg] = fmaxf(hv, 0.f) + h1r[nt][rg];
            }
        }
    }
    __syncthreads();   // all waves done reading W1A/W1B

    // ---------------- h2 -> block-wide transposed planes (hi @W1A, lo @W1B) ----------------
    #pragma unroll
    for (int nt = 0; nt < 8; nt++){
        int k = nt*16 + l16;
        #pragma unroll
        for (int rg = 0; rg < 4; rg++){
            int row = 16*w + q*4 + rg;
            float val = h1r[nt][rg];
            unsigned short hi = f2bf(val);
            int addr = row*256 + ((((k>>3) ^ (row&15)) & 15)*16) + (k&7)*2;
            *(unsigned short*)(smem + W1A + addr) = hi;
            *(unsigned short*)(smem + W1B + addr) = f2bf(val - bf2f(hi));
        }
    }
    __syncthreads();

    // ---------------- phase 3: wave-independent, 8 dims/wave, no barriers ----------------
    const char* wpl = ws + WS_WP + lane*16;
    const float* bpf = (const float*)(ws + WS_BP);
    float* xuLf = (float*)(smem + XU);
    float* yuLf = (float*)(smem + XM);
    const uint4 zero4 = {0,0,0,0};
    const bool pok = (lane & 31) < 25;
    const int hh = lane >> 5;
    const int d0 = w*8;
    const int rA = (lane & 31)*256, rB = (32 + (lane & 31))*256;
    auto rdB = [&](int pl, int rbase, int oct){
        return *(const bf16x8*)(smem + pl + rbase + (((oct ^ l16) & 15)*16));
    };
    uint4 A0[8], A1[8];
    #pragma unroll
    for (int kk = 0; kk < 8; kk++){ A0[kk] = zero4; A1[kk] = zero4; }
    if (pok){
        #pragma unroll
        for (int kk = 0; kk < 4; kk++){
            A0[kk]   = *(const uint4*)(wpl + d0*16384 + kk*1024);
            A0[4+kk] = *(const uint4*)(wpl + d0*16384 + 8192 + kk*1024);
        }
    }
    float ld_acc = 0.f;   // accumulated in log2 units; x ln2 at epilogue
    for (int i = 0; i < 8; i++){
        int c = d0 + i;
        if (pok){
            #pragma unroll
            for (int kk = 0; kk < 4; kk++){
                A1[kk]   = *(const uint4*)(wpl + c*16384 + (4+kk)*1024);
                A1[4+kk] = *(const uint4*)(wpl + c*16384 + 8192 + (4+kk)*1024);
            }
        }
        f32x16 t0, t1;
        #pragma unroll
        for (int z = 0; z < 16; z++){ t0[z] = 0.f; t1[z] = 0.f; }
        #pragma unroll
        for (int kk = 0; kk < 4; kk++){
            int oct = kk*2 + hh;
            bf16x8 ahh = *(bf16x8*)&A0[kk];
            bf16x8 all = *(bf16x8*)&A0[4+kk];
            bf16x8 b0h = rdB(W1A, rA, oct), b0l = rdB(W1B, rA, oct);
            bf16x8 b1h = rdB(W1A, rB, oct), b1l = rdB(W1B, rB, oct);
            t0 = MFMA32(ahh, b0l, t0); t1 = MFMA32(ahh, b1l, t1);
            t0 = MFMA32(all, b0h, t0); t1 = MFMA32(all, b1h, t1);
            t0 = MFMA32(ahh, b0h, t0); t1 = MFMA32(ahh, b1h, t1);
        }
        if (i < 7 && pok){
            #pragma unroll
            for (int kk = 0; kk < 4; kk++){
                A0[kk]   = *(const uint4*)(wpl + (c+1)*16384 + kk*1024);
                A0[4+kk] = *(const uint4*)(wpl + (c+1)*16384 + 8192 + kk*1024);
            }
        }
        #pragma unroll
        for (int kk = 0; kk < 4; kk++){
            int oct = (4+kk)*2 + hh;
            bf16x8 ahh = *(bf16x8*)&A1[kk];
            bf16x8 all = *(bf16x8*)&A1[4+kk];
            bf16x8 b0h = rdB(W1A, rA, oct), b0l = rdB(W1B, rA, oct);
            bf16x8 b1h = rdB(W1A, rB, oct), b1l = rdB(W1B, rB, oct);
            t0 = MFMA32(ahh, b0l, t0); t1 = MFMA32(ahh, b1l, t1);
            t0 = MFMA32(all, b0h, t0); t1 = MFMA32(all, b1h, t1);
            t0 = MFMA32(ahh, b0h, t0); t1 = MFMA32(ahh, b1h, t1);
        }
        // ---- pairwise spline: lanes (L, L^32) jointly handle rows L&31 (tile0) and 32+(L&31) (tile1)
        float xu0 = xuLf[c*64 + (lane & 31)];
        float xu1 = xuLf[c*64 + 32 + (lane & 31)];
        float xc0 = __builtin_amdgcn_fmed3f(xu0, -3.f, 3.f);
        float xc1 = __builtin_amdgcn_fmed3f(xu1, -3.f, 3.f);
        float4 bq0 = *(const float4*)(bpf + c*32 + 0  + 4*hh);
        float4 bq1 = *(const float4*)(bpf + c*32 + 8  + 4*hh);
        float4 bq2 = *(const float4*)(bpf + c*32 + 16 + 4*hh);
        float  bq3 = bpf[c*32 + 24 + 4*hh];
        float wv0[4], wv1[4], hv0[4], hv1[4], dv0[4], dv1[4];
        #pragma unroll
        for (int jj = 0; jj < 4; jj++){
            wv0[jj] = t0[jj] + bq0[jj];  hv0[jj] = t0[4+jj] + bq1[jj];  dv0[jj] = t0[8+jj] + bq2[jj];
            wv1[jj] = t1[jj] + bq0[jj];  hv1[jj] = t1[4+jj] + bq1[jj];  dv1[jj] = t1[8+jj] + bq2[jj];
        }
        float dx0 = t0[12] + bq3, dx1 = t1[12] + bq3;
        float bd0 = __shfl_xor(hh ? dv0[0] : dx0, 32, 64);
        float bd1 = __shfl_xor(hh ? dv1[0] : dx1, 32, 64);
        // softmax without max-subtraction: logits prescaled by 1/ln2 at prep,
        // so raw v_exp_f32 (2^x) == e^logit; LN-bounded => no overflow risk.
        auto softscale = [&](float* a){
            float e0 = __builtin_amdgcn_exp2f(a[0]), e1 = __builtin_amdgcn_exp2f(a[1]);
            float e2 = __builtin_amdgcn_exp2f(a[2]), e3 = __builtin_amdgcn_exp2f(a[3]);
            float s = (e0+e1)+(e2+e3);
            s += __shfl_xor(s, 32, 64);
            float sc = 5.952f * __builtin_amdgcn_rcpf(s);
            a[0] = fmaf(e0, sc, 0.006f); a[1] = fmaf(e1, sc, 0.006f);
            a[2] = fmaf(e2, sc, 0.006f); a[3] = fmaf(e3, sc, 0.006f);
        };
        softscale(wv0); softscale(hv0); softscale(wv1); softscale(hv1);
        auto candf = [&](float* wv, float* hv, float* dv, float bdr, float xc,
                         float& X, float& Y, float& W, float& H, float& DK, float& DK1, float& V){
            float pw0 = wv[0], pw1 = pw0+wv[1], pw2 = pw1+wv[2], pw3 = pw2+wv[3];
            float ph0 = hv[0], ph1 = ph0+hv[1], ph2 = ph1+hv[2], ph3 = ph2+hv[3];
            float offw = __shfl_xor(pw3, 32, 64);
            float offh = __shfl_xor(ph3, 32, 64);
            float bw = hh ? (offw - 3.f) : -3.f;
            float by = hh ? (offh - 3.f) : -3.f;
            X = bw; Y = by; W = wv[0]; H = hv[0]; DK = dv[0]; DK1 = dv[1];
            float e1_ = bw + pw0, e2_ = bw + pw1, e3_ = bw + pw2;
            if (xc >= e1_){ X = e1_; Y = by + ph0; W = wv[1]; H = hv[1]; DK = dv[1]; DK1 = dv[2]; }
            if (xc >= e2_){ X = e2_; Y = by + ph1; W = wv[2]; H = hv[2]; DK = dv[2]; DK1 = dv[3]; }
            if (xc >= e3_){ X = e3_; Y = by + ph2; W = wv[3]; H = hv[3]; DK = dv[3]; DK1 = bdr;  }
            V = (!hh || xc >= bw) ? 1.f : 0.f;
        };
        float X0,Y0,Wc0,Hc0,K0,K10,V0, X1,Y1,Wc1,Hc1,K1,K11,V1;
        candf(wv0, hv0, dv0, bd0, xc0, X0,Y0,Wc0,Hc0,K0,K10,V0);
        candf(wv1, hv1, dv1, bd1, xc1, X1,Y1,Wc1,Hc1,K1,K11,V1);
        float rX  = __shfl_xor(hh ? X0  : X1 , 32, 64);
        float rY  = __shfl_xor(hh ? Y0  : Y1 , 32, 64);
        float rW  = __shfl_xor(hh ? Wc0 : Wc1, 32, 64);
        float rH  = __shfl_xor(hh ? Hc0 : Hc1, 32, 64);
        float rK  = __shfl_xor(hh ? K0  : K1 , 32, 64);
        float rK1 = __shfl_xor(hh ? K10 : K11, 32, 64);
        float rV  = __shfl_xor(hh ? V0  : V1 , 32, 64);
        float oX  = hh ? X1  : X0,  oY  = hh ? Y1  : Y0,  oW = hh ? Wc1 : Wc0;
        float oH  = hh ? Hc1 : Hc0, oK  = hh ? K1  : K0,  oK1 = hh ? K11 : K10;
        float oV  = hh ? V1  : V0;
        bool useh1 = ((hh ? oV : rV) > 0.5f);
        bool useOwn = (hh != 0) == useh1;
        float X = useOwn ? oX : rX,  Y = useOwn ? oY : rY;
        float W = useOwn ? oW : rW,  H = useOwn ? oH : rH;
        float K = useOwn ? oK : rK,  K1s = useOwn ? oK1 : rK1;
        float xu = hh ? xu1 : xu0;
        float xc = hh ? xc1 : xc0;
        // softplus in exp2/log2 domain is NOT used here (K arrives in e-domain):
        float DKs  = fmaxf(K, 0.f)   + __logf(1.f + __expf(-fabsf(K)))   + 0.001f;
        float DK1s = fmaxf(K1s, 0.f) + __logf(1.f + __expf(-fabsf(K1s))) + 0.001f;
        float iw = __builtin_amdgcn_rcpf(W);
        float s_ = H * iw;
        float th = (xc - X) * iw;
        float om = 1.f - th;
        float t1m = th * om;
        float den = s_ + (DK1s + DKs - 2.f*s_) * t1m;
        float rden = __builtin_amdgcn_rcpf(den);
        float yin = Y + H * (s_*th*th + DKs*t1m) * rden;
        float num2 = DK1s*th*th + 2.f*s_*t1m + DKs*om*om;
        float ldin = 2.f*__logf(s_) + __logf(num2) - 2.f*__logf(den);
        bool inside = (xu > -3.f) && (xu < 3.f);
        yuLf[c*64 + lane] = inside ? yin : xu;   // lane L finalizes global row L
        ld_acc += inside ? ldin : 0.f;
    }

    // ---------------- epilogue ----------------
    __syncthreads();                       // xu dead; yu complete
    *(float*)(smem + XU + (w*64 + lane)*4) = ld_acc;
    __syncthreads();
    if (t < 64){
        const float* lp = (const float*)(smem + XU);
        ldout[r0 + t] = (lp[t] + lp[64 + t]) + (lp[128 + t] + lp[192 + t]);
    }
    {
        int row = t >> 2, part = t & 3;
        const float* xrow = x + (size_t)(r0 + row)*64;
        float* yrow = yout + (size_t)(r0 + row)*64;
        const float* yuL = (const float*)(smem + XM);
        #pragma unroll
        for (int j = 0; j < 4; j++){
            int s = part*4 + j;
            float4 xv = ((const float4*)xrow)[s];
            float4 o;
            o.x = xv.x; o.z = xv.z;
            o.y = yuL[(2*s)*64 + row];
            o.w = yuL[(2*s+1)*64 + row];
            ((float4*)yrow)[s] = o;
        }
    }
}

extern "C" void kernel_launch(void* const* d_in, const int* in_sizes, int n_in,
                              void* d_out, int out_size, void* d_ws, size_t ws_size,
                              hipStream_t stream)
{
    const float* x   = (const float*)d_in[0];
    const float* W0  = (const float*)d_in[1];
    const float* b0  = (const float*)d_in[2];
    const float* g0  = (const float*)d_in[3];
    const float* be0 = (const float*)d_in[4];
    const float* W1  = (const float*)d_in[5];
    const float* b1  = (const float*)d_in[6];
    const float* g1  = (const float*)d_in[7];
    const float* be1 = (const float*)d_in[8];
    const float* Wp  = (const float*)d_in[9];
    const float* bp  = (const float*)d_in[10];
    float* y = (float*)d_out;
    float* ldo = y + (size_t)NROWS * 64;
    char* ws = (char*)d_ws;

    hipLaunchKernelGGL(prep_kernel, dim3(152), dim3(256), 0, stream, W0, W1, Wp, bp, ws);
    hipLaunchKernelGGL(main_kernel, dim3(4096), dim3(256), 0, stream,
                       x, b0, g0, be0, b1, g1, be1, ws, y, ldo);
}